// Round 2
// baseline (501.403 us; speedup 1.0000x reference)
//
#include <hip/hip_runtime.h>
#include <hip/hip_bf16.h>

#define BN 4096
#define II 64
#define DD 128
#define ID (II*DD)      // 8192
#define BM 128
#define BT (BN/BM)      // 32

typedef __attribute__((ext_vector_type(8))) short short8;
typedef __attribute__((ext_vector_type(4))) float f32x4;

// round-to-nearest-even f32 -> bf16 (finite inputs)
__device__ __forceinline__ short f2bf(float x) {
    unsigned int u = __float_as_uint(x);
    unsigned int r = (u + 0x7FFFu + ((u >> 16) & 1u)) >> 16;
    return (short)r;
}

__device__ __forceinline__ float sigf(float x) {
    return __fdividef(1.0f, 1.0f + __expf(-x));
}
__device__ __forceinline__ float tanhfast(float x) {
    return __fdividef(2.0f, 1.0f + __expf(-2.0f * x)) - 1.0f;
}

// Transpose/convert U (I,D,D) f32 row-major -> bf16 MFMA B-fragment order.
// Fragment index: ((g*II+i)*32 + kk*8 + nf)*64 + lane, each 8 bf16 (16B).
// B-fragment: lane holds U[i][ kk*32 + (lane>>4)*8 + e ][ nf*16 + (lane&15) ]
__global__ void prep_U(const float* __restrict__ Ur, const float* __restrict__ Uz,
                       const float* __restrict__ Uh, short* __restrict__ out) {
    int bx = blockIdx.x;                 // ((g*64 + i)*4 + kk)*8 + nf
    int nf = bx & 7;
    int kk = (bx >> 3) & 3;
    int i  = (bx >> 5) & 63;
    int g  = bx >> 11;
    int lane = threadIdx.x;              // 0..63
    int lr = lane & 15, lg = lane >> 4;
    const float* U = (g == 0) ? Ur : (g == 1) ? Uz : Uh;
    const float* src = U + (size_t)i * DD * DD + (size_t)(kk * 32 + lg * 8) * DD + nf * 16 + lr;
    short8 v;
#pragma unroll
    for (int e = 0; e < 8; ++e) v[e] = f2bf(src[(size_t)e * DD]);
    short8* dst = (short8*)out;
    dst[(size_t)bx * 64 + lane] = v;
}

__global__ __launch_bounds__(256, 2)
void gru_main(const float* __restrict__ X, const float* __restrict__ M,
              const float* __restrict__ h,
              const float* __restrict__ Wr, const float* __restrict__ Wz,
              const float* __restrict__ Wh,
              const float* __restrict__ br, const float* __restrict__ bz,
              const float* __restrict__ bh,
              const short* __restrict__ Ut, float* __restrict__ out) {
    const int bx   = blockIdx.x;
    const int i    = bx >> 5;            // weight index 0..63
    const int bt   = bx & 31;            // batch tile
    const int tid  = threadIdx.x;
    const int lane = tid & 63;
    const int w    = tid >> 6;           // wave 0..3
    const int lr   = lane & 15;
    const int lg   = lane >> 4;

    __shared__ short rh_lds[BM][DD + 8]; // +8 pad breaks bank aliasing

    const int row0 = bt * BM + w * 32;   // this wave's 32-row strip

    const short8* UtF = (const short8*)Ut;
    // frag idx = (g*64+i)*2048 + kk*512 + nf*64 + lane
    const size_t ub = (size_t)i * 2048 + lane;

    // ---------------- Phase A: acc_r, acc_z = h @ U_r , h @ U_z ----------------
    f32x4 accr[2][8], accz[2][8];
#pragma unroll
    for (int m = 0; m < 2; ++m)
#pragma unroll
        for (int n = 0; n < 8; ++n) {
            accr[m][n] = (f32x4){0.f, 0.f, 0.f, 0.f};
            accz[m][n] = (f32x4){0.f, 0.f, 0.f, 0.f};
        }

    const float* hA0 = h + (size_t)(row0 + lr) * ID + i * DD;
    const float* hA1 = hA0 + (size_t)16 * ID;

#pragma unroll
    for (int kk = 0; kk < 4; ++kk) {
        const int col = kk * 32 + lg * 8;
        short8 a[2];
        {
            const f32x4* p0 = (const f32x4*)(hA0 + col);
            const f32x4* p1 = (const f32x4*)(hA1 + col);
            f32x4 u0 = p0[0], u1 = p0[1];
            f32x4 v0 = p1[0], v1 = p1[1];
#pragma unroll
            for (int e = 0; e < 4; ++e) {
                a[0][e]     = f2bf(u0[e]);
                a[0][e + 4] = f2bf(u1[e]);
                a[1][e]     = f2bf(v0[e]);
                a[1][e + 4] = f2bf(v1[e]);
            }
        }
#pragma unroll
        for (int n = 0; n < 8; ++n) {
            short8 brf = UtF[ub + (size_t)0 * 131072 + kk * 512 + n * 64];
            short8 bzf = UtF[ub + (size_t)1 * 131072 + kk * 512 + n * 64];
#pragma unroll
            for (int m = 0; m < 2; ++m) {
                accr[m][n] = __builtin_amdgcn_mfma_f32_16x16x32_bf16(a[m], brf, accr[m][n], 0, 0, 0);
                accz[m][n] = __builtin_amdgcn_mfma_f32_16x16x32_bf16(a[m], bzf, accz[m][n], 0, 0, 0);
            }
        }
    }

    // per-row X values (rows row0 + m*16 + lg*4 + reg)
    float x0a[2][4], x1a[2][4];
#pragma unroll
    for (int m = 0; m < 2; ++m)
#pragma unroll
        for (int reg = 0; reg < 4; ++reg) {
            int row = row0 + m * 16 + lg * 4 + reg;
            const float* xp = X + ((size_t)row * II + i) * 2;
            x0a[m][reg] = xp[0];
            x1a[m][reg] = xp[1];
        }

    // epilogue A: r = sigmoid(...), rh -> LDS (bf16); z = sigmoid(...) kept in regs
#pragma unroll
    for (int n = 0; n < 8; ++n) {
        const int d = n * 16 + lr;
        const float wr0 = Wr[(i * 2 + 0) * DD + d];
        const float wr1 = Wr[(i * 2 + 1) * DD + d];
        const float brv = br[i * DD + d];
        const float wz0 = Wz[(i * 2 + 0) * DD + d];
        const float wz1 = Wz[(i * 2 + 1) * DD + d];
        const float bzv = bz[i * DD + d];
#pragma unroll
        for (int m = 0; m < 2; ++m)
#pragma unroll
            for (int reg = 0; reg < 4; ++reg) {
                int lrow = w * 32 + m * 16 + lg * 4 + reg;
                int row  = bt * BM + lrow;
                float rv = sigf(accr[m][n][reg] + x0a[m][reg] * wr0 + x1a[m][reg] * wr1 + brv);
                float hv = h[(size_t)row * ID + i * DD + d];
                rh_lds[lrow][d] = f2bf(rv * hv);
                float zv = sigf(accz[m][n][reg] + x0a[m][reg] * wz0 + x1a[m][reg] * wz1 + bzv);
                accz[m][n][reg] = zv;
            }
    }
    __syncthreads();

    // ---------------- Phase B: acc_h = (r*h) @ U_h ----------------
    f32x4 acch[2][8];
#pragma unroll
    for (int m = 0; m < 2; ++m)
#pragma unroll
        for (int n = 0; n < 8; ++n) acch[m][n] = (f32x4){0.f, 0.f, 0.f, 0.f};

#pragma unroll
    for (int kk = 0; kk < 4; ++kk) {
        short8 a[2];
#pragma unroll
        for (int m = 0; m < 2; ++m)
            a[m] = *(const short8*)&rh_lds[w * 32 + m * 16 + lr][kk * 32 + lg * 8];
#pragma unroll
        for (int n = 0; n < 8; ++n) {
            short8 bhf = UtF[ub + (size_t)2 * 131072 + kk * 512 + n * 64];
#pragma unroll
            for (int m = 0; m < 2; ++m)
                acch[m][n] = __builtin_amdgcn_mfma_f32_16x16x32_bf16(a[m], bhf, acch[m][n], 0, 0, 0);
        }
    }

    // final epilogue: h_tilde = tanh(...); blend with f32 hr and M; write out
    float mva[2][4];
#pragma unroll
    for (int m = 0; m < 2; ++m)
#pragma unroll
        for (int reg = 0; reg < 4; ++reg) {
            int row = row0 + m * 16 + lg * 4 + reg;
            mva[m][reg] = M[(size_t)row * II + i];
        }

#pragma unroll
    for (int n = 0; n < 8; ++n) {
        const int d = n * 16 + lr;
        const float wh0 = Wh[(i * 2 + 0) * DD + d];
        const float wh1 = Wh[(i * 2 + 1) * DD + d];
        const float bhv = bh[i * DD + d];
#pragma unroll
        for (int m = 0; m < 2; ++m)
#pragma unroll
            for (int reg = 0; reg < 4; ++reg) {
                int row = row0 + m * 16 + lg * 4 + reg;
                float ht = tanhfast(acch[m][n][reg] + x0a[m][reg] * wh0 + x1a[m][reg] * wh1 + bhv);
                float zv = accz[m][n][reg];
                float hv = h[(size_t)row * ID + i * DD + d];
                float mv = mva[m][reg];
                float hnew = zv * hv + (1.0f - zv) * ht;
                out[(size_t)row * ID + i * DD + d] = hv * (1.0f - mv) + hnew * mv;
            }
    }
}

extern "C" void kernel_launch(void* const* d_in, const int* in_sizes, int n_in,
                              void* d_out, int out_size, void* d_ws, size_t ws_size,
                              hipStream_t stream) {
    const float* X  = (const float*)d_in[0];
    const float* M  = (const float*)d_in[1];
    const float* h  = (const float*)d_in[2];
    const float* Wr = (const float*)d_in[3];
    const float* Wz = (const float*)d_in[4];
    const float* Wh = (const float*)d_in[5];
    const float* Ur = (const float*)d_in[6];
    const float* Uz = (const float*)d_in[7];
    const float* Uh = (const float*)d_in[8];
    const float* br = (const float*)d_in[9];
    const float* bz = (const float*)d_in[10];
    const float* bh = (const float*)d_in[11];
    float* out = (float*)d_out;
    short* Ut  = (short*)d_ws;           // 3*64*128*128*2 = 6 MB bf16 fragments

    prep_U<<<3 * II * 4 * 8, 64, 0, stream>>>(Ur, Uz, Uh, Ut);
    gru_main<<<II * BT, 256, 0, stream>>>(X, M, h, Wr, Wz, Wh, br, bz, bh, Ut, out);
}

// Round 4
// 315.764 us; speedup vs baseline: 1.5879x; 1.5879x over previous
//
#include <hip/hip_runtime.h>
#include <hip/hip_bf16.h>

#define II 64
#define DD 128
#define ID (II*DD)      // 8192
#define NIT 16          // row-tiles per block
#define RPT 16          // rows per tile

typedef __attribute__((ext_vector_type(8))) short short8;
typedef __attribute__((ext_vector_type(4))) float f32x4;

__device__ __forceinline__ short f2bf(float x) {
    __hip_bfloat16 b = __float2bfloat16(x);
    return __builtin_bit_cast(short, b);
}
__device__ __forceinline__ float sigf(float x) {
    return __fdividef(1.0f, 1.0f + __expf(-x));
}
__device__ __forceinline__ float tanhfast(float x) {
    return __fdividef(2.0f, 1.0f + __expf(-2.0f * x)) - 1.0f;
}

// Transpose/convert U (I,D,D) f32 row-major -> bf16 MFMA B-fragment order.
// Fragment index: ((g*II+i)*32 + kk*8 + nf)*64 + lane, each 8 bf16 (16B).
// B-fragment: lane holds U[i][ kk*32 + (lane>>4)*8 + e ][ nf*16 + (lane&15) ]
__global__ void prep_U(const float* __restrict__ Ur, const float* __restrict__ Uz,
                       const float* __restrict__ Uh, short* __restrict__ out) {
    int bx = blockIdx.x;                 // ((g*64 + i)*4 + kk)*8 + nf
    int nf = bx & 7;
    int kk = (bx >> 3) & 3;
    int i  = (bx >> 5) & 63;
    int g  = bx >> 11;
    int lane = threadIdx.x;              // 0..63
    int lr = lane & 15, lg = lane >> 4;
    const float* U = (g == 0) ? Ur : (g == 1) ? Uz : Uh;
    const float* src = U + (size_t)i * DD * DD + (size_t)(kk * 32 + lg * 8) * DD + nf * 16 + lr;
    short8 v;
#pragma unroll
    for (int e = 0; e < 8; ++e) v[e] = f2bf(src[(size_t)e * DD]);
    short8* dst = (short8*)out;
    dst[(size_t)bx * 64 + lane] = v;
}

// Column-partitioned GRU block: 4 waves x 32 cols; U in registers; h staged
// global->reg->LDS one tile ahead; rh exchanged via LDS.
__global__ __launch_bounds__(256, 2)
void gru_main(const float* __restrict__ X, const float* __restrict__ M,
              const float* __restrict__ h,
              const float* __restrict__ Wr, const float* __restrict__ Wz,
              const float* __restrict__ Wh,
              const float* __restrict__ br, const float* __restrict__ bz,
              const float* __restrict__ bh,
              const short* __restrict__ Ut, float* __restrict__ out) {
    // XCD swizzle: all 16 blocks of one i on the same XCD (i in [8x, 8x+8)).
    const int b   = blockIdx.x;          // 0..1023
    const int x   = b & 7;
    const int r   = b >> 3;              // 0..127
    const int i   = x * 8 + (r >> 4);    // 0..63
    const int tb  = r & 15;              // 0..15
    const int row0b = tb * (NIT * RPT);  // block's first row (256-row span)

    const int tid  = threadIdx.x;
    const int lane = tid & 63;
    const int wv   = tid >> 6;           // 0..3
    const int lr   = lane & 15;
    const int lg   = lane >> 4;          // 0..3
    const int colbase = wv * 32;

    __shared__ float hbuf[2][16 * 132];  // h tile, padded rows (528B stride)
    __shared__ short rhb[16 * 136];      // rh tile bf16, padded (272B stride)

    // ---- preload U B-fragments for this wave's 32 cols: 24 frags = 96 VGPRs
    const short8* UtF = (const short8*)Ut;
    short8 Bf[3][4][2];
#pragma unroll
    for (int g = 0; g < 3; ++g)
#pragma unroll
        for (int kk = 0; kk < 4; ++kk)
#pragma unroll
            for (int nt = 0; nt < 2; ++nt)
                Bf[g][kk][nt] = UtF[(size_t)(g * 64 + i) * 2048 + kk * 512 + (2 * wv + nt) * 64 + lane];

    // ---- hoist W, b for this lane's 2 columns
    float wts[3][2][2], bias[3][2];
    {
        const float* Wg[3] = {Wr, Wz, Wh};
        const float* bg[3] = {br, bz, bh};
#pragma unroll
        for (int g = 0; g < 3; ++g)
#pragma unroll
            for (int nt = 0; nt < 2; ++nt) {
                int c = colbase + nt * 16 + lr;
                wts[g][nt][0] = Wg[g][(size_t)i * 256 + c];
                wts[g][nt][1] = Wg[g][(size_t)i * 256 + 128 + c];
                bias[g][nt]   = bg[g][(size_t)i * 128 + c];
            }
    }

    const float2* Xp = (const float2*)X;

    // ---- prologue: stage tile 0 into hbuf[0]
    {
        const float* hb = h + (size_t)row0b * ID + (size_t)i * DD;
        f32x4 sA = *(const f32x4*)(hb + (size_t)(tid >> 5) * ID + (tid & 31) * 4);
        f32x4 sB = *(const f32x4*)(hb + (size_t)(8 + (tid >> 5)) * ID + (tid & 31) * 4);
        float* db = &hbuf[0][0];
        *(f32x4*)(db + (tid >> 5) * 132 + (tid & 31) * 4) = sA;
        *(f32x4*)(db + (8 + (tid >> 5)) * 132 + (tid & 31) * 4) = sB;
    }

    for (int t = 0; t < NIT; ++t) {
        const int r0 = row0b + t * RPT;
        const int nb = (t + 1) & 1;
        const bool more = (t + 1) < NIT;

        // issue next tile's global loads early (T14: issue-early / write-late)
        f32x4 sA, sB;
        if (more) {
            const float* hb = h + (size_t)(row0b + (t + 1) * RPT) * ID + (size_t)i * DD;
            sA = *(const f32x4*)(hb + (size_t)(tid >> 5) * ID + (tid & 31) * 4);
            sB = *(const f32x4*)(hb + (size_t)(8 + (tid >> 5)) * ID + (tid & 31) * 4);
        }

        __syncthreads();   // barrier1: hbuf[t&1] visible, rhb free

        const float* cbuf = &hbuf[t & 1][0];

        // ---- phase A: acc_r, acc_z over this wave's 32 cols
        f32x4 accr[2], accz[2], acch[2];
#pragma unroll
        for (int nt = 0; nt < 2; ++nt) {
            accr[nt] = (f32x4){0.f, 0.f, 0.f, 0.f};
            accz[nt] = (f32x4){0.f, 0.f, 0.f, 0.f};
            acch[nt] = (f32x4){0.f, 0.f, 0.f, 0.f};
        }
#pragma unroll
        for (int kk = 0; kk < 4; ++kk) {
            const float* ap = cbuf + lr * 132 + kk * 32 + lg * 8;
            f32x4 u0 = *(const f32x4*)ap;
            f32x4 u1 = *(const f32x4*)(ap + 4);
            short8 a;
#pragma unroll
            for (int e = 0; e < 4; ++e) { a[e] = f2bf(u0[e]); a[e + 4] = f2bf(u1[e]); }
#pragma unroll
            for (int nt = 0; nt < 2; ++nt) {
                accr[nt] = __builtin_amdgcn_mfma_f32_16x16x32_bf16(a, Bf[0][kk][nt], accr[nt], 0, 0, 0);
                accz[nt] = __builtin_amdgcn_mfma_f32_16x16x32_bf16(a, Bf[1][kk][nt], accz[nt], 0, 0, 0);
            }
        }

        // ---- epilogue A: r, z; rh -> LDS; keep z, hv, X in regs
        float x0a[4], x1a[4], hva[2][4];
#pragma unroll
        for (int reg = 0; reg < 4; ++reg) {
            const int row  = lg * 4 + reg;
            const int grow = r0 + row;
            float2 xv = Xp[(size_t)grow * II + i];
            x0a[reg] = xv.x; x1a[reg] = xv.y;
#pragma unroll
            for (int nt = 0; nt < 2; ++nt) {
                const int c = colbase + nt * 16 + lr;
                float hv = cbuf[row * 132 + c];
                hva[nt][reg] = hv;
                float rv = sigf(accr[nt][reg] + x0a[reg] * wts[0][nt][0] + x1a[reg] * wts[0][nt][1] + bias[0][nt]);
                rhb[row * 136 + c] = f2bf(rv * hv);
                accz[nt][reg] = sigf(accz[nt][reg] + x0a[reg] * wts[1][nt][0] + x1a[reg] * wts[1][nt][1] + bias[1][nt]);
            }
        }

        __syncthreads();   // barrier2: rhb ready; hbuf[nb] safe to overwrite

        // write-late: park next h tile into LDS while phase B runs
        if (more) {
            float* db = &hbuf[nb][0];
            *(f32x4*)(db + (tid >> 5) * 132 + (tid & 31) * 4) = sA;
            *(f32x4*)(db + (8 + (tid >> 5)) * 132 + (tid & 31) * 4) = sB;
        }

        // ---- phase B: acc_h = rh @ U_h
#pragma unroll
        for (int kk = 0; kk < 4; ++kk) {
            short8 pa = *(const short8*)&rhb[lr * 136 + kk * 32 + lg * 8];
#pragma unroll
            for (int nt = 0; nt < 2; ++nt)
                acch[nt] = __builtin_amdgcn_mfma_f32_16x16x32_bf16(pa, Bf[2][kk][nt], acch[nt], 0, 0, 0);
        }

        // ---- epilogue B: tanh, blend, store
#pragma unroll
        for (int reg = 0; reg < 4; ++reg) {
            const int grow = r0 + lg * 4 + reg;
            const float mv = M[(size_t)grow * II + i];
#pragma unroll
            for (int nt = 0; nt < 2; ++nt) {
                const int c = colbase + nt * 16 + lr;
                float ht = tanhfast(acch[nt][reg] + x0a[reg] * wts[2][nt][0] + x1a[reg] * wts[2][nt][1] + bias[2][nt]);
                float zv = accz[nt][reg];
                float hv = hva[nt][reg];
                float hnew = zv * hv + (1.0f - zv) * ht;
                out[(size_t)grow * ID + (size_t)i * DD + c] = hv * (1.0f - mv) + hnew * mv;
            }
        }
    }
}

extern "C" void kernel_launch(void* const* d_in, const int* in_sizes, int n_in,
                              void* d_out, int out_size, void* d_ws, size_t ws_size,
                              hipStream_t stream) {
    const float* X  = (const float*)d_in[0];
    const float* M  = (const float*)d_in[1];
    const float* h  = (const float*)d_in[2];
    const float* Wr = (const float*)d_in[3];
    const float* Wz = (const float*)d_in[4];
    const float* Wh = (const float*)d_in[5];
    const float* Ur = (const float*)d_in[6];
    const float* Uz = (const float*)d_in[7];
    const float* Uh = (const float*)d_in[8];
    const float* br = (const float*)d_in[9];
    const float* bz = (const float*)d_in[10];
    const float* bh = (const float*)d_in[11];
    float* out = (float*)d_out;
    short* Ut  = (short*)d_ws;           // 3*64*128*128*2 = 6 MB bf16 fragments

    prep_U<<<3 * II * 4 * 8, 64, 0, stream>>>(Ur, Uz, Uh, Ut);
    gru_main<<<64 * 16, 256, 0, stream>>>(X, M, h, Wr, Wz, Wh, br, bz, bh, Ut, out);
}

// Round 6
// 314.986 us; speedup vs baseline: 1.5918x; 1.0025x over previous
//
#include <hip/hip_runtime.h>
#include <hip/hip_bf16.h>

#define II 64
#define DD 128
#define ID (II*DD)      // 8192
#define NIT 8           // row-tiles per block
#define RPT 16          // rows per tile
#define BROWS (NIT*RPT) // 128 rows per block

typedef __attribute__((ext_vector_type(8))) short short8;
typedef __attribute__((ext_vector_type(4))) float f32x4;

__device__ __forceinline__ short f2bf(float x) {
    __hip_bfloat16 b = __float2bfloat16(x);
    return __builtin_bit_cast(short, b);
}
__device__ __forceinline__ float sigf(float x) {
    return __fdividef(1.0f, 1.0f + __expf(-x));
}
__device__ __forceinline__ float tanhfast(float x) {
    return __fdividef(2.0f, 1.0f + __expf(-2.0f * x)) - 1.0f;
}

// Transpose/convert U (I,D,D) f32 row-major -> bf16 MFMA B-fragment order.
// Fragment index: ((g*II+i)*32 + kk*8 + nf)*64 + lane, each 8 bf16 (16B).
// B-fragment: lane holds U[i][ kk*32 + (lane>>4)*8 + e ][ nf*16 + (lane&15) ]
__global__ void prep_U(const float* __restrict__ Ur, const float* __restrict__ Uz,
                       const float* __restrict__ Uh, short* __restrict__ out) {
    int bx = blockIdx.x;                 // ((g*64 + i)*4 + kk)*8 + nf
    int nf = bx & 7;
    int kk = (bx >> 3) & 3;
    int i  = (bx >> 5) & 63;
    int g  = bx >> 11;
    int lane = threadIdx.x;              // 0..63
    int lr = lane & 15, lg = lane >> 4;
    const float* U = (g == 0) ? Ur : (g == 1) ? Uz : Uh;
    const float* src = U + (size_t)i * DD * DD + (size_t)(kk * 32 + lg * 8) * DD + nf * 16 + lr;
    short8 v;
#pragma unroll
    for (int e = 0; e < 8; ++e) v[e] = f2bf(src[(size_t)e * DD]);
    short8* dst = (short8*)out;
    dst[(size_t)bx * 64 + lane] = v;
}

// Column-partitioned GRU block: 4 waves x 32 cols; U in registers; h staged
// global->reg->LDS one tile ahead; X/M prefetched into registers one tile
// ahead (same issue-early pattern as h; no extra LDS, no extra barriers).
__global__ __launch_bounds__(256, 2)
void gru_main(const float* __restrict__ X, const float* __restrict__ M,
              const float* __restrict__ h,
              const float* __restrict__ Wr, const float* __restrict__ Wz,
              const float* __restrict__ Wh,
              const float* __restrict__ br, const float* __restrict__ bz,
              const float* __restrict__ bh,
              const short* __restrict__ Ut, float* __restrict__ out) {
    // XCD swizzle: all 32 blocks of one i on the same XCD (i in [8x, 8x+8)).
    const int b   = blockIdx.x;          // 0..2047
    const int x   = b & 7;
    const int r   = b >> 3;              // 0..255
    const int i   = x * 8 + (r >> 5);    // 0..63
    const int tb  = r & 31;              // 0..31
    const int row0b = tb * BROWS;        // block's first row (128-row span)

    const int tid  = threadIdx.x;
    const int lane = tid & 63;
    const int wv   = tid >> 6;           // 0..3
    const int lr   = lane & 15;
    const int lg   = lane >> 4;          // 0..3
    const int colbase = wv * 32;

    __shared__ float hbuf[2][16 * 132];  // h tile, padded rows (528B stride)
    __shared__ short rhb[16 * 136];      // rh tile bf16, padded (272B stride)

    // ---- preload U B-fragments for this wave's 32 cols: 24 frags = 96 VGPRs
    const short8* UtF = (const short8*)Ut;
    short8 Bf[3][4][2];
#pragma unroll
    for (int g = 0; g < 3; ++g)
#pragma unroll
        for (int kk = 0; kk < 4; ++kk)
#pragma unroll
            for (int nt = 0; nt < 2; ++nt)
                Bf[g][kk][nt] = UtF[(size_t)(g * 64 + i) * 2048 + kk * 512 + (2 * wv + nt) * 64 + lane];

    // ---- hoist W, b for this lane's 2 columns
    float wts[3][2][2], bias[3][2];
    {
        const float* Wg[3] = {Wr, Wz, Wh};
        const float* bg[3] = {br, bz, bh};
#pragma unroll
        for (int g = 0; g < 3; ++g)
#pragma unroll
            for (int nt = 0; nt < 2; ++nt) {
                int c = colbase + nt * 16 + lr;
                wts[g][nt][0] = Wg[g][(size_t)i * 256 + c];
                wts[g][nt][1] = Wg[g][(size_t)i * 256 + 128 + c];
                bias[g][nt]   = bg[g][(size_t)i * 128 + c];
            }
    }

    const float2* Xp = (const float2*)X;

    // ---- prologue: stage tile 0 into hbuf[0]; prefetch tile-0 X/M to regs
    {
        const float* hb = h + (size_t)row0b * ID + (size_t)i * DD;
        f32x4 sA = *(const f32x4*)(hb + (size_t)(tid >> 5) * ID + (tid & 31) * 4);
        f32x4 sB = *(const f32x4*)(hb + (size_t)(8 + (tid >> 5)) * ID + (tid & 31) * 4);
        float* db = &hbuf[0][0];
        *(f32x4*)(db + (tid >> 5) * 132 + (tid & 31) * 4) = sA;
        *(f32x4*)(db + (8 + (tid >> 5)) * 132 + (tid & 31) * 4) = sB;
    }
    float px0[4], px1[4], pmv[4];
#pragma unroll
    for (int reg = 0; reg < 4; ++reg) {
        const int grow = row0b + lg * 4 + reg;
        float2 xv = Xp[(size_t)grow * II + i];
        px0[reg] = xv.x; px1[reg] = xv.y;
        pmv[reg] = M[(size_t)grow * II + i];
    }

    for (int t = 0; t < NIT; ++t) {
        const int nb = (t + 1) & 1;
        const bool more = (t + 1) < NIT;

        // issue next tile's loads early (T14: issue-early / write-late)
        f32x4 sA, sB;
        float nx0[4], nx1[4], nmv[4];
        if (more) {
            const float* hb = h + (size_t)(row0b + (t + 1) * RPT) * ID + (size_t)i * DD;
            sA = *(const f32x4*)(hb + (size_t)(tid >> 5) * ID + (tid & 31) * 4);
            sB = *(const f32x4*)(hb + (size_t)(8 + (tid >> 5)) * ID + (tid & 31) * 4);
            const int rbase = row0b + (t + 1) * RPT + lg * 4;
#pragma unroll
            for (int reg = 0; reg < 4; ++reg) {
                float2 xv = Xp[(size_t)(rbase + reg) * II + i];
                nx0[reg] = xv.x; nx1[reg] = xv.y;
                nmv[reg] = M[(size_t)(rbase + reg) * II + i];
            }
        }

        __syncthreads();   // barrier1: hbuf[t&1] visible, rhb free

        const float* cbuf = &hbuf[t & 1][0];

        // ---- phase A: acc_r, acc_z over this wave's 32 cols
        f32x4 accr[2], accz[2], acch[2];
#pragma unroll
        for (int nt = 0; nt < 2; ++nt) {
            accr[nt] = (f32x4){0.f, 0.f, 0.f, 0.f};
            accz[nt] = (f32x4){0.f, 0.f, 0.f, 0.f};
            acch[nt] = (f32x4){0.f, 0.f, 0.f, 0.f};
        }
#pragma unroll
        for (int kk = 0; kk < 4; ++kk) {
            const float* ap = cbuf + lr * 132 + kk * 32 + lg * 8;
            f32x4 u0 = *(const f32x4*)ap;
            f32x4 u1 = *(const f32x4*)(ap + 4);
            short8 a;
#pragma unroll
            for (int e = 0; e < 4; ++e) { a[e] = f2bf(u0[e]); a[e + 4] = f2bf(u1[e]); }
#pragma unroll
            for (int nt = 0; nt < 2; ++nt) {
                accr[nt] = __builtin_amdgcn_mfma_f32_16x16x32_bf16(a, Bf[0][kk][nt], accr[nt], 0, 0, 0);
                accz[nt] = __builtin_amdgcn_mfma_f32_16x16x32_bf16(a, Bf[1][kk][nt], accz[nt], 0, 0, 0);
            }
        }

        // ---- epilogue A: r, z; rh -> LDS; keep z, hv in regs
        float hva[2][4];
#pragma unroll
        for (int reg = 0; reg < 4; ++reg) {
            const int row = lg * 4 + reg;        // row within tile
#pragma unroll
            for (int nt = 0; nt < 2; ++nt) {
                const int c = colbase + nt * 16 + lr;
                float hv = cbuf[row * 132 + c];
                hva[nt][reg] = hv;
                float rv = sigf(accr[nt][reg] + px0[reg] * wts[0][nt][0] + px1[reg] * wts[0][nt][1] + bias[0][nt]);
                rhb[row * 136 + c] = f2bf(rv * hv);
                accz[nt][reg] = sigf(accz[nt][reg] + px0[reg] * wts[1][nt][0] + px1[reg] * wts[1][nt][1] + bias[1][nt]);
            }
        }

        __syncthreads();   // barrier2: rhb ready; hbuf[nb] safe to overwrite

        // write-late: park next h tile into LDS while phase B runs
        if (more) {
            float* db = &hbuf[nb][0];
            *(f32x4*)(db + (tid >> 5) * 132 + (tid & 31) * 4) = sA;
            *(f32x4*)(db + (8 + (tid >> 5)) * 132 + (tid & 31) * 4) = sB;
        }

        // ---- phase B: acc_h = rh @ U_h
#pragma unroll
        for (int kk = 0; kk < 4; ++kk) {
            short8 pa = *(const short8*)&rhb[lr * 136 + kk * 32 + lg * 8];
#pragma unroll
            for (int nt = 0; nt < 2; ++nt)
                acch[nt] = __builtin_amdgcn_mfma_f32_16x16x32_bf16(pa, Bf[2][kk][nt], acch[nt], 0, 0, 0);
        }

        // ---- epilogue B: tanh, blend, store
#pragma unroll
        for (int reg = 0; reg < 4; ++reg) {
            const int grow = row0b + t * RPT + lg * 4 + reg;
            const float mv = pmv[reg];
#pragma unroll
            for (int nt = 0; nt < 2; ++nt) {
                const int c = colbase + nt * 16 + lr;
                float ht = tanhfast(acch[nt][reg] + px0[reg] * wts[2][nt][0] + px1[reg] * wts[2][nt][1] + bias[2][nt]);
                float zv = accz[nt][reg];
                float hv = hva[nt][reg];
                float hnew = zv * hv + (1.0f - zv) * ht;
                out[(size_t)grow * ID + (size_t)i * DD + c] = hv * (1.0f - mv) + hnew * mv;
            }
        }

        // rotate X/M prefetch registers
        if (more) {
#pragma unroll
            for (int reg = 0; reg < 4; ++reg) {
                px0[reg] = nx0[reg]; px1[reg] = nx1[reg]; pmv[reg] = nmv[reg];
            }
        }
    }
}

extern "C" void kernel_launch(void* const* d_in, const int* in_sizes, int n_in,
                              void* d_out, int out_size, void* d_ws, size_t ws_size,
                              hipStream_t stream) {
    const float* X  = (const float*)d_in[0];
    const float* M  = (const float*)d_in[1];
    const float* h  = (const float*)d_in[2];
    const float* Wr = (const float*)d_in[3];
    const float* Wz = (const float*)d_in[4];
    const float* Wh = (const float*)d_in[5];
    const float* Ur = (const float*)d_in[6];
    const float* Uz = (const float*)d_in[7];
    const float* Uh = (const float*)d_in[8];
    const float* br = (const float*)d_in[9];
    const float* bz = (const float*)d_in[10];
    const float* bh = (const float*)d_in[11];
    float* out = (float*)d_out;
    short* Ut  = (short*)d_ws;           // 3*64*128*128*2 = 6 MB bf16 fragments

    prep_U<<<3 * II * 4 * 8, 64, 0, stream>>>(Ur, Uz, Uh, Ut);
    gru_main<<<64 * 32, 256, 0, stream>>>(X, M, h, Wr, Wz, Wh, br, bz, bh, Ut, out);
}